// Round 3
// baseline (101.341 us; speedup 1.0000x reference)
//
#include <hip/hip_runtime.h>

// SimplifyLoss: Chamfer-style loss, fused pair pass + single reduce.
// preds: [8, 2048, 3] f32, gts: [8, 8192, 3] f32, out: scalar f32.
//
// d[b,i,j] = ||gt_i - pred_j||^2 = gg_i + (pp_j - 2*dot(g_i,p_j))
// loss = mean_{b,j} colmin + mean_{b,i} rowmin + mean_b max_j colmin
//
// K1 pair_k: grid 1024 = (b, gtblk of 128 gts, pred-half). Per block: 8 steps
//   of 128 preds staged in LDS as (-2x,-2y,-2z,pp) SoA. Thread = (tx pred-slot
//   0..15, ty gt-group 0..15): 8 gts fixed in regs as float2-packed (v_pk_*),
//   8 preds/step. Row-mins kept packed in regs all kernel; col-mins per step
//   shfl-reduced over ty and stored as partials. Also zero-inits the ws
//   accumulators consumed by K2 (safe: kernel-boundary ordering).
// K2 red_k: grid (8,9). y<8: colmin over 64 gtblks for 256 preds -> chunk
//   sum+max -> atomicAdd(acc)/atomicMax(bmax[b]). y==8: row sum (min of 2
//   pred-halves) -> atomicAdd(acc). Completion counter: 72nd block writes
//   out[0] = acc + mean_b(bmax). No separate fin kernel, no init kernel.

#define BB 8
#define MM 2048
#define NN 8192

typedef float v2f __attribute__((ext_vector_type(2)));

__global__ __launch_bounds__(256, 4) void pair_k(const float* __restrict__ preds,
                                                 const float* __restrict__ gts,
                                                 float* __restrict__ rowpart,
                                                 float* __restrict__ colpart,
                                                 float* __restrict__ acc,
                                                 unsigned* __restrict__ bmax,
                                                 unsigned* __restrict__ cnt) {
    const int blk   = blockIdx.x;
    const int b     = blk >> 7;
    const int gtblk = (blk >> 1) & 63;
    const int ph    = blk & 1;          // pred half (0/1)
    const int tid   = threadIdx.x;
    const int tx    = tid >> 4;         // pred slot group 0..15
    const int ty    = tid & 15;         // gt group 0..15 (= lane bits 0..3)

    if (blk == 0 && tid < 16) {
        if (tid == 0) { acc[0] = 0.0f; cnt[0] = 0u; }
        if (tid < 8) bmax[tid] = 0u;    // 0-bits == 0.0f, identity for max of >=0
    }

    __shared__ float sm2x[128], sm2y[128], sm2z[128], spp[128];
    __shared__ float red[16 * 128];

    // My 8 gts (24 contiguous floats) via 6 float4 loads -> packed float2.
    v2f gx2[4], gy2[4], gz2[4], gg2[4], rmin2[4];
    {
        const float4* g4 = (const float4*)(gts + (size_t)(b * NN + gtblk * 128 + ty * 8) * 3);
        float4 a0 = g4[0], a1 = g4[1], a2 = g4[2], a3 = g4[3], a4 = g4[4], a5 = g4[5];
        float gx[8], gy[8], gz[8];
        gx[0] = a0.x; gy[0] = a0.y; gz[0] = a0.z;
        gx[1] = a0.w; gy[1] = a1.x; gz[1] = a1.y;
        gx[2] = a1.z; gy[2] = a1.w; gz[2] = a2.x;
        gx[3] = a2.y; gy[3] = a2.z; gz[3] = a2.w;
        gx[4] = a3.x; gy[4] = a3.y; gz[4] = a3.z;
        gx[5] = a3.w; gy[5] = a4.x; gz[5] = a4.y;
        gx[6] = a4.z; gy[6] = a4.w; gz[6] = a5.x;
        gx[7] = a5.y; gy[7] = a5.z; gz[7] = a5.w;
#pragma unroll
        for (int ip = 0; ip < 4; ++ip) {
            gx2[ip] = (v2f){gx[2 * ip], gx[2 * ip + 1]};
            gy2[ip] = (v2f){gy[2 * ip], gy[2 * ip + 1]};
            gz2[ip] = (v2f){gz[2 * ip], gz[2 * ip + 1]};
            gg2[ip] = __builtin_elementwise_fma(gx2[ip], gx2[ip],
                      __builtin_elementwise_fma(gy2[ip], gy2[ip], gz2[ip] * gz2[ip]));
            rmin2[ip] = (v2f){3.4e38f, 3.4e38f};
        }
    }

    const float* pbase = preds + (size_t)(b * MM + ph * 1024) * 3;

    for (int step = 0; step < 8; ++step) {
        float lx = 0.f, ly = 0.f, lz = 0.f;
        if (tid < 128) {
            const float* p = pbase + (size_t)(step * 128 + tid) * 3;
            lx = p[0]; ly = p[1]; lz = p[2];
        }
        __syncthreads();   // prior step's readers done
        if (tid < 128) {
            sm2x[tid] = -2.0f * lx;
            sm2y[tid] = -2.0f * ly;
            sm2z[tid] = -2.0f * lz;
            spp[tid]  = fmaf(lx, lx, fmaf(ly, ly, lz * lz));
        }
        __syncthreads();

        v2f cmin2[8];
#pragma unroll
        for (int j = 0; j < 8; ++j) cmin2[j] = (v2f){3.4e38f, 3.4e38f};

#pragma unroll
        for (int j = 0; j < 8; ++j) {
            const int pj = tx * 8 + j;
            const float vx = sm2x[pj], vy = sm2y[pj], vz = sm2z[pj], vp = spp[pj];
            const v2f px2 = (v2f){vx, vx};
            const v2f py2 = (v2f){vy, vy};
            const v2f pz2 = (v2f){vz, vz};
            const v2f pp2 = (v2f){vp, vp};
#pragma unroll
            for (int ip = 0; ip < 4; ++ip) {
                v2f t = __builtin_elementwise_fma(gx2[ip], px2, pp2);
                t     = __builtin_elementwise_fma(gy2[ip], py2, t);
                t     = __builtin_elementwise_fma(gz2[ip], pz2, t);
                v2f d = gg2[ip] + t;
                rmin2[ip] = __builtin_elementwise_min(rmin2[ip], d);
                cmin2[j]  = __builtin_elementwise_min(cmin2[j], d);
            }
        }

        // cmin: pack-pair collapse, then reduce across ty (lane bits 0..3).
        float cmin[8];
#pragma unroll
        for (int j = 0; j < 8; ++j) cmin[j] = fminf(cmin2[j].x, cmin2[j].y);
#pragma unroll
        for (int m = 1; m < 16; m <<= 1) {
#pragma unroll
            for (int j = 0; j < 8; ++j)
                cmin[j] = fminf(cmin[j], __shfl_xor(cmin[j], m, 64));
        }
        if (ty == 0) {
            float4* dst = (float4*)&colpart[((size_t)b * 64 + gtblk) * MM +
                                            ph * 1024 + step * 128 + tx * 8];
            dst[0] = make_float4(cmin[0], cmin[1], cmin[2], cmin[3]);
            dst[1] = make_float4(cmin[4], cmin[5], cmin[6], cmin[7]);
        }
    }

    // Row-min cross-tx reduce, store this pred-half's partial.
    __syncthreads();
#pragma unroll
    for (int ip = 0; ip < 4; ++ip) {
        red[tx * 128 + ty * 8 + 2 * ip]     = rmin2[ip].x;
        red[tx * 128 + ty * 8 + 2 * ip + 1] = rmin2[ip].y;
    }
    __syncthreads();
    if (tid < 128) {
        float m = red[tid];
#pragma unroll
        for (int k = 1; k < 16; ++k) m = fminf(m, red[k * 128 + tid]);
        rowpart[((size_t)b * 2 + ph) * NN + gtblk * 128 + tid] = m;
    }
}

__global__ __launch_bounds__(256) void red_k(const float* __restrict__ rowpart,
                                             const float* __restrict__ colpart,
                                             float* __restrict__ acc,
                                             unsigned* __restrict__ bmax,
                                             unsigned* __restrict__ cnt,
                                             float* __restrict__ out) {
    const int b = blockIdx.x, y = blockIdx.y, tid = threadIdx.x;
    __shared__ float a1[4], a2[4];

    if (y < 8) {
        const int p = y * 256 + tid;
        const float* cp = colpart + (size_t)b * 64 * MM + p;
        float m = 3.4e38f;
#pragma unroll 8
        for (int g = 0; g < 64; ++g) m = fminf(m, cp[(size_t)g * MM]);
        float s = m, mx = m;
#pragma unroll
        for (int o = 32; o > 0; o >>= 1) {
            s += __shfl_down(s, o, 64);
            mx = fmaxf(mx, __shfl_down(mx, o, 64));
        }
        const int w = tid >> 6, lane = tid & 63;
        if (lane == 0) { a1[w] = s; a2[w] = mx; }
        __syncthreads();
        if (tid == 0) {
            float cs = a1[0] + a1[1] + a1[2] + a1[3];
            float cm = fmaxf(fmaxf(a2[0], a2[1]), fmaxf(a2[2], a2[3]));
            atomicAdd(acc, cs / (float)(BB * MM));          // loss_1 contribution
            atomicMax(&bmax[b], __float_as_uint(cm));       // per-batch col max
        }
    } else {
        const float* r = rowpart + (size_t)b * 2 * NN;
        float s = 0.0f;
        for (int i = tid; i < NN; i += 256) s += fminf(r[i], r[NN + i]);
#pragma unroll
        for (int o = 32; o > 0; o >>= 1) s += __shfl_down(s, o, 64);
        const int w = tid >> 6, lane = tid & 63;
        if (lane == 0) a1[w] = s;
        __syncthreads();
        if (tid == 0)
            atomicAdd(acc, (a1[0] + a1[1] + a1[2] + a1[3]) / (float)(BB * NN)); // loss_2
    }

    if (tid == 0) {
        __threadfence();
        unsigned old = atomicAdd(cnt, 1u);
        if (old == 71u) {                    // last of 72 blocks
            __threadfence();
            float a = atomicAdd(acc, 0.0f);  // fetch final sum
            float mm = 0.0f;
#pragma unroll
            for (int bb = 0; bb < 8; ++bb)
                mm += __uint_as_float(atomicMax(&bmax[bb], 0u));
            out[0] = a + mm / (float)BB;     // + loss_m
        }
    }
}

extern "C" void kernel_launch(void* const* d_in, const int* in_sizes, int n_in,
                              void* d_out, int out_size, void* d_ws, size_t ws_size,
                              hipStream_t stream) {
    const float* preds = (const float*)d_in[0];
    const float* gts   = (const float*)d_in[1];
    float* out = (float*)d_out;

    // ws (floats): rowpart[2*8*8192] | colpart[8*64*2048] | acc[1] | bmax[8] | cnt[1]
    float* rowpart = (float*)d_ws;
    float* colpart = rowpart + (size_t)2 * BB * NN;
    float* acc     = colpart + (size_t)BB * 64 * MM;
    unsigned* bmax = (unsigned*)(acc + 1);
    unsigned* cnt  = bmax + 8;

    pair_k<<<1024, 256, 0, stream>>>(preds, gts, rowpart, colpart, acc, bmax, cnt);
    red_k<<<dim3(BB, 9), 256, 0, stream>>>(rowpart, colpart, acc, bmax, cnt, out);
}

// Round 4
// 96.080 us; speedup vs baseline: 1.0548x; 1.0548x over previous
//
#include <hip/hip_runtime.h>

// SimplifyLoss: Chamfer-style loss, fused pair pass + single reduce.
// preds: [8, 2048, 3] f32, gts: [8, 8192, 3] f32, out: scalar f32.
//
// d[b,i,j] = ||gt_i - pred_j||^2 = gg_i + (pp_j - 2*dot(g_i,p_j))
// loss = mean_{b,j} colmin + mean_{b,i} rowmin + mean_b max_j colmin
//
// K1 pair_k: grid 1024 = (b, gtblk of 128 gts, pred-half of 1024). ALL 1024
//   preds staged once in LDS as (-2x,-2y,-2z,pp) float4, padded idx=q+(q>>3)
//   so the wave's 4 tx-groups hit distinct banks -> conflict-free b128
//   broadcasts, and the 8-step main loop has NO barriers. Thread = (tx
//   pred-slot 0..15, ty gt-group 0..15): 8 gts fixed in regs (v2f packed for
//   v_pk_fma_f32), 8 preds/step from LDS. Row-mins in regs all kernel;
//   col-mins per step shfl-reduced over ty (lane bits 0..3) -> partials.
// K2 red_k: grid (8,9). y<8: colmin over 64 gtblks -> chunk sum+max ->
//   atomicAdd(acc)/atomicMax(bmax). y==8: row sum of min(2 halves). 72nd
//   block writes out[0] = acc + mean_b(bmax). No init kernel (pair_k blk 0
//   zero-inits ws accumulators; safe via kernel-boundary ordering).

#define BB 8
#define MM 2048
#define NN 8192

typedef float v2f __attribute__((ext_vector_type(2)));

__device__ __forceinline__ int pad_idx(int q) { return q + (q >> 3); }

__global__ __launch_bounds__(256, 4) void pair_k(const float* __restrict__ preds,
                                                 const float* __restrict__ gts,
                                                 float* __restrict__ rowpart,
                                                 float* __restrict__ colpart,
                                                 float* __restrict__ acc,
                                                 unsigned* __restrict__ bmax,
                                                 unsigned* __restrict__ cnt) {
    const int blk   = blockIdx.x;
    const int b     = blk >> 7;
    const int gtblk = (blk >> 1) & 63;
    const int ph    = blk & 1;          // pred half (0/1)
    const int tid   = threadIdx.x;
    const int tx    = tid >> 4;         // pred slot group 0..15
    const int ty    = tid & 15;         // gt group 0..15 (= lane bits 0..3)

    if (blk == 0 && tid < 16) {
        if (tid == 0) { acc[0] = 0.0f; cnt[0] = 0u; }
        if (tid < 8) bmax[tid] = 0u;    // 0-bits == 0.0f, identity for max >= 0
    }

    // 1024 preds as (-2x,-2y,-2z,pp), padded every 8 entries (18.4 KB).
    __shared__ float4 sp4[1152];

    // Stage all preds of this half once: 4 preds (12 floats, 3x b128) per thread.
    {
        const float4* pg = (const float4*)(preds + (size_t)(b * MM + ph * 1024) * 3);
        float4 r0 = pg[tid * 3 + 0], r1 = pg[tid * 3 + 1], r2 = pg[tid * 3 + 2];
        float x[4], y[4], z[4];
        x[0] = r0.x; y[0] = r0.y; z[0] = r0.z;
        x[1] = r0.w; y[1] = r1.x; z[1] = r1.y;
        x[2] = r1.z; y[2] = r1.w; z[2] = r2.x;
        x[3] = r2.y; y[3] = r2.z; z[3] = r2.w;
#pragma unroll
        for (int k = 0; k < 4; ++k) {
            const int q = tid * 4 + k;
            sp4[pad_idx(q)] = make_float4(-2.0f * x[k], -2.0f * y[k], -2.0f * z[k],
                                          fmaf(x[k], x[k], fmaf(y[k], y[k], z[k] * z[k])));
        }
    }

    // My 8 gts (24 contiguous floats, 6x b128) -> v2f packed + ||g||^2.
    v2f gx2[4], gy2[4], gz2[4], gg2[4], rmin2[4];
    {
        const float4* g4 = (const float4*)(gts + (size_t)(b * NN + gtblk * 128 + ty * 8) * 3);
        float4 a0 = g4[0], a1 = g4[1], a2 = g4[2], a3 = g4[3], a4 = g4[4], a5 = g4[5];
        float gx[8], gy[8], gz[8];
        gx[0] = a0.x; gy[0] = a0.y; gz[0] = a0.z;
        gx[1] = a0.w; gy[1] = a1.x; gz[1] = a1.y;
        gx[2] = a1.z; gy[2] = a1.w; gz[2] = a2.x;
        gx[3] = a2.y; gy[3] = a2.z; gz[3] = a2.w;
        gx[4] = a3.x; gy[4] = a3.y; gz[4] = a3.z;
        gx[5] = a3.w; gy[5] = a4.x; gz[5] = a4.y;
        gx[6] = a4.z; gy[6] = a4.w; gz[6] = a5.x;
        gx[7] = a5.y; gy[7] = a5.z; gz[7] = a5.w;
#pragma unroll
        for (int ip = 0; ip < 4; ++ip) {
            gx2[ip] = (v2f){gx[2 * ip], gx[2 * ip + 1]};
            gy2[ip] = (v2f){gy[2 * ip], gy[2 * ip + 1]};
            gz2[ip] = (v2f){gz[2 * ip], gz[2 * ip + 1]};
            gg2[ip] = __builtin_elementwise_fma(gx2[ip], gx2[ip],
                      __builtin_elementwise_fma(gy2[ip], gy2[ip], gz2[ip] * gz2[ip]));
            rmin2[ip] = (v2f){3.4e38f, 3.4e38f};
        }
    }

    __syncthreads();   // preds staged; no barriers needed inside main loop

    for (int step = 0; step < 8; ++step) {
        v2f cmin2[8];
#pragma unroll
        for (int j = 0; j < 8; ++j) cmin2[j] = (v2f){3.4e38f, 3.4e38f};

#pragma unroll
        for (int j = 0; j < 8; ++j) {
            const float4 p = sp4[pad_idx(step * 128 + tx * 8 + j)];
            const v2f px2 = (v2f){p.x, p.x};
            const v2f py2 = (v2f){p.y, p.y};
            const v2f pz2 = (v2f){p.z, p.z};
            const v2f pp2 = (v2f){p.w, p.w};
#pragma unroll
            for (int ip = 0; ip < 4; ++ip) {
                v2f t = __builtin_elementwise_fma(gx2[ip], px2, pp2);
                t     = __builtin_elementwise_fma(gy2[ip], py2, t);
                t     = __builtin_elementwise_fma(gz2[ip], pz2, t);
                v2f d = gg2[ip] + t;
                rmin2[ip] = __builtin_elementwise_min(rmin2[ip], d);
                cmin2[j]  = __builtin_elementwise_min(cmin2[j], d);
            }
        }

        // Collapse pack-pair, reduce across ty (lane bits 0..3), store partial.
        float cmin[8];
#pragma unroll
        for (int j = 0; j < 8; ++j) cmin[j] = fminf(cmin2[j].x, cmin2[j].y);
#pragma unroll
        for (int m = 1; m < 16; m <<= 1) {
#pragma unroll
            for (int j = 0; j < 8; ++j)
                cmin[j] = fminf(cmin[j], __shfl_xor(cmin[j], m, 64));
        }
        if (ty == 0) {
            float4* dst = (float4*)&colpart[((size_t)b * 64 + gtblk) * MM +
                                            ph * 1024 + step * 128 + tx * 8];
            dst[0] = make_float4(cmin[0], cmin[1], cmin[2], cmin[3]);
            dst[1] = make_float4(cmin[4], cmin[5], cmin[6], cmin[7]);
        }
    }

    // Row-min cross-tx reduce; reuse sp4 as scratch (2048 floats needed).
    float* red = (float*)sp4;
    __syncthreads();   // all waves done reading sp4 as preds
#pragma unroll
    for (int ip = 0; ip < 4; ++ip) {
        red[tx * 128 + ty * 8 + 2 * ip]     = rmin2[ip].x;
        red[tx * 128 + ty * 8 + 2 * ip + 1] = rmin2[ip].y;
    }
    __syncthreads();
    if (tid < 128) {
        float m = red[tid];
#pragma unroll
        for (int k = 1; k < 16; ++k) m = fminf(m, red[k * 128 + tid]);
        rowpart[((size_t)b * 2 + ph) * NN + gtblk * 128 + tid] = m;
    }
}

__global__ __launch_bounds__(256) void red_k(const float* __restrict__ rowpart,
                                             const float* __restrict__ colpart,
                                             float* __restrict__ acc,
                                             unsigned* __restrict__ bmax,
                                             unsigned* __restrict__ cnt,
                                             float* __restrict__ out) {
    const int b = blockIdx.x, y = blockIdx.y, tid = threadIdx.x;
    __shared__ float a1[4], a2[4];

    if (y < 8) {
        const int p = y * 256 + tid;
        const float* cp = colpart + (size_t)b * 64 * MM + p;
        float m = 3.4e38f;
#pragma unroll 8
        for (int g = 0; g < 64; ++g) m = fminf(m, cp[(size_t)g * MM]);
        float s = m, mx = m;
#pragma unroll
        for (int o = 32; o > 0; o >>= 1) {
            s += __shfl_down(s, o, 64);
            mx = fmaxf(mx, __shfl_down(mx, o, 64));
        }
        const int w = tid >> 6, lane = tid & 63;
        if (lane == 0) { a1[w] = s; a2[w] = mx; }
        __syncthreads();
        if (tid == 0) {
            float cs = a1[0] + a1[1] + a1[2] + a1[3];
            float cm = fmaxf(fmaxf(a2[0], a2[1]), fmaxf(a2[2], a2[3]));
            atomicAdd(acc, cs / (float)(BB * MM));          // loss_1 contribution
            atomicMax(&bmax[b], __float_as_uint(cm));       // per-batch col max
        }
    } else {
        const float* r = rowpart + (size_t)b * 2 * NN;
        float s = 0.0f;
        for (int i = tid; i < NN; i += 256) s += fminf(r[i], r[NN + i]);
#pragma unroll
        for (int o = 32; o > 0; o >>= 1) s += __shfl_down(s, o, 64);
        const int w = tid >> 6, lane = tid & 63;
        if (lane == 0) a1[w] = s;
        __syncthreads();
        if (tid == 0)
            atomicAdd(acc, (a1[0] + a1[1] + a1[2] + a1[3]) / (float)(BB * NN)); // loss_2
    }

    if (tid == 0) {
        __threadfence();
        unsigned old = atomicAdd(cnt, 1u);
        if (old == 71u) {                    // last of 72 blocks
            __threadfence();
            float a = atomicAdd(acc, 0.0f);  // fetch final sum
            float mm = 0.0f;
#pragma unroll
            for (int bb = 0; bb < 8; ++bb)
                mm += __uint_as_float(atomicMax(&bmax[bb], 0u));
            out[0] = a + mm / (float)BB;     // + loss_m
        }
    }
}

extern "C" void kernel_launch(void* const* d_in, const int* in_sizes, int n_in,
                              void* d_out, int out_size, void* d_ws, size_t ws_size,
                              hipStream_t stream) {
    const float* preds = (const float*)d_in[0];
    const float* gts   = (const float*)d_in[1];
    float* out = (float*)d_out;

    // ws (floats): rowpart[2*8*8192] | colpart[8*64*2048] | acc[1] | bmax[8] | cnt[1]
    float* rowpart = (float*)d_ws;
    float* colpart = rowpart + (size_t)2 * BB * NN;
    float* acc     = colpart + (size_t)BB * 64 * MM;
    unsigned* bmax = (unsigned*)(acc + 1);
    unsigned* cnt  = bmax + 8;

    pair_k<<<1024, 256, 0, stream>>>(preds, gts, rowpart, colpart, acc, bmax, cnt);
    red_k<<<dim3(BB, 9), 256, 0, stream>>>(rowpart, colpart, acc, bmax, cnt, out);
}